// Round 1
// baseline (147.014 us; speedup 1.0000x reference)
//
#include <hip/hip_runtime.h>

#define BATCH 1024
#define INSZ 4096
#define SQ 128
#define EM 32
#define NH 8
#define TPB 256

typedef __attribute__((ext_vector_type(8))) __bf16 bf16x8;
typedef __attribute__((ext_vector_type(4))) float f32x4;
typedef __attribute__((ext_vector_type(4))) unsigned short us4;

__device__ __forceinline__ unsigned short f2b(float f) {
  unsigned u = __float_as_uint(f);
  u += 0x7fffu + ((u >> 16) & 1u);
  return (unsigned short)(u >> 16);
}
__device__ __forceinline__ float b2f(unsigned short h) {
  return __uint_as_float(((unsigned)h) << 16);
}

// Padded leading dims (bf16 elems): rows stay 16B-aligned, break pow-2 bank strides.
#define LDT 40    // for [128][32] tiles (t, q, prod)
#define LDW 136   // for [x][128] tiles (scores, vT)

__global__ void cvt_w(const float* __restrict__ wq, const float* __restrict__ wk,
                      const float* __restrict__ wv, const float* __restrict__ wo,
                      unsigned short* __restrict__ ws) {
  int i = blockIdx.x * blockDim.x + threadIdx.x;  // 0..32767
  const float* src = (i < 8192) ? wq : (i < 16384) ? wk : (i < 24576) ? wv : wo;
  ws[i] = f2b(src[i & 8191]);
}

__global__ __launch_bounds__(TPB, 2) void mha_fused(
    const float* __restrict__ x, const float* __restrict__ gamma,
    const float* __restrict__ beta, const float* __restrict__ bq,
    const float* __restrict__ bk, const float* __restrict__ bv,
    const float* __restrict__ bo, const unsigned short* __restrict__ wbf,
    float* __restrict__ out) {
  __shared__ __align__(16) unsigned short t_lds[SQ * LDT];  // xn  [128][32]
  __shared__ __align__(16) unsigned short qh[SQ * LDT];     // q (scaled) / later prod
  __shared__ __align__(16) unsigned short kh[SQ * LDT];     // k
  __shared__ __align__(16) unsigned short vT[EM * LDW];     // v^T [32][128]
  __shared__ __align__(16) unsigned short sc[SQ * LDW];     // scores->exp [128][128]
  __shared__ float red[2 * SQ];
  __shared__ float red2[8];

  const int b = blockIdx.x;
  const int tid = threadIdx.x;
  const int lane = tid & 63;
  const int wid = tid >> 6;   // 4 waves; wave w owns rows [32w, 32w+32)
  const int l15 = lane & 15;
  const int lh = lane >> 4;   // 0..3

  const unsigned short* wqb = wbf;
  const unsigned short* wkb = wbf + 8192;
  const unsigned short* wvb = wbf + 16384;
  const unsigned short* wob = wbf + 24576;  // [32][256] row-major

  const float* xb = x + b * INSZ;
  const f32x4 fz = {0.f, 0.f, 0.f, 0.f};
  const float SCL = 0.17677669529663687f;  // 1/sqrt(32)

  // ---------------- LayerNorm ----------------
  float xv[16];
  float s = 0.f, sq = 0.f;
#pragma unroll
  for (int i = 0; i < 4; ++i) {
    float4 a = ((const float4*)(xb + tid * 16))[i];
    xv[4 * i] = a.x; xv[4 * i + 1] = a.y; xv[4 * i + 2] = a.z; xv[4 * i + 3] = a.w;
  }
#pragma unroll
  for (int i = 0; i < 16; ++i) { s += xv[i]; sq += xv[i] * xv[i]; }
#pragma unroll
  for (int o = 32; o > 0; o >>= 1) { s += __shfl_down(s, o); sq += __shfl_down(sq, o); }
  if (lane == 0) { red2[wid] = s; red2[4 + wid] = sq; }
  __syncthreads();
  s = red2[0] + red2[1] + red2[2] + red2[3];
  sq = red2[4] + red2[5] + red2[6] + red2[7];
  const float mu = s * (1.f / INSZ);
  const float var = fmaxf(sq * (1.f / INSZ) - mu * mu, 0.f);
  const float rs = rsqrtf(var + 1e-5f);
  {
    int base = tid * 16;
#pragma unroll
    for (int i = 0; i < 16; ++i) {
      int idx = base + i;
      float xn = (xv[i] - mu) * rs * gamma[idx] + beta[idx];
      t_lds[(idx >> 5) * LDT + (idx & 31)] = f2b(xn);
    }
  }
  __syncthreads();

  f32x4 oacc[2][2];
#pragma unroll
  for (int i = 0; i < 2; ++i)
#pragma unroll
    for (int j = 0; j < 2; ++j) oacc[i][j] = fz;

  const int r0 = wid * 32;

  for (int h = 0; h < NH; ++h) {
    // ---------------- Q,K,V projections (per-head slices) ----------------
#pragma unroll
    for (int mt = 0; mt < 2; ++mt) {
      int rr = r0 + mt * 16;
      bf16x8 a = *(const bf16x8*)&t_lds[(rr + l15) * LDT + lh * 8];
#pragma unroll
      for (int nt = 0; nt < 2; ++nt) {
        int f0 = h * 32 + nt * 16;
        // Q (scale folded in)
        bf16x8 bw = *(const bf16x8*)&wqb[(f0 + l15) * 32 + lh * 8];
        f32x4 d = __builtin_amdgcn_mfma_f32_16x16x32_bf16(a, bw, fz, 0, 0, 0);
        float bias = bq[f0 + l15];
#pragma unroll
        for (int r = 0; r < 4; ++r)
          qh[(rr + lh * 4 + r) * LDT + nt * 16 + l15] = f2b((d[r] + bias) * SCL);
        // K
        bw = *(const bf16x8*)&wkb[(f0 + l15) * 32 + lh * 8];
        d = __builtin_amdgcn_mfma_f32_16x16x32_bf16(a, bw, fz, 0, 0, 0);
        bias = bk[f0 + l15];
#pragma unroll
        for (int r = 0; r < 4; ++r)
          kh[(rr + lh * 4 + r) * LDT + nt * 16 + l15] = f2b(d[r] + bias);
        // V -> transposed store (packed b64)
        bw = *(const bf16x8*)&wvb[(f0 + l15) * 32 + lh * 8];
        d = __builtin_amdgcn_mfma_f32_16x16x32_bf16(a, bw, fz, 0, 0, 0);
        bias = bv[f0 + l15];
        us4 pk;
#pragma unroll
        for (int r = 0; r < 4; ++r) pk[r] = f2b(d[r] + bias);
        *(us4*)&vT[(nt * 16 + l15) * LDW + rr + lh * 4] = pk;
      }
    }
    __syncthreads();

    // ---------------- scores = q @ k^T (pre-scaled) ----------------
#pragma unroll
    for (int mt = 0; mt < 2; ++mt) {
      int rr = r0 + mt * 16;
      bf16x8 a = *(const bf16x8*)&qh[(rr + l15) * LDT + lh * 8];
#pragma unroll
      for (int jt = 0; jt < 8; ++jt) {
        bf16x8 bk8 = *(const bf16x8*)&kh[(jt * 16 + l15) * LDT + lh * 8];
        f32x4 d = __builtin_amdgcn_mfma_f32_16x16x32_bf16(a, bk8, fz, 0, 0, 0);
#pragma unroll
        for (int r = 0; r < 4; ++r)
          sc[(rr + lh * 4 + r) * LDW + jt * 16 + l15] = f2b(d[r]);
      }
    }
    __syncthreads();

    // ------- softmax over QUERY axis (per column j), 2 threads/column -------
    {
      int j = tid & 127;
      int half = tid >> 7;
      int ib = half * 64;
      float m0 = -3e38f, m1 = -3e38f;
#pragma unroll 8
      for (int ii = 0; ii < 64; ii += 2) {
        m0 = fmaxf(m0, b2f(sc[(ib + ii) * LDW + j]));
        m1 = fmaxf(m1, b2f(sc[(ib + ii + 1) * LDW + j]));
      }
      red[half * 128 + j] = fmaxf(m0, m1);
      __syncthreads();
      float mg = fmaxf(red[j], red[128 + j]);
      __syncthreads();  // WAR: everyone read maxes before sums overwrite
      float sum = 0.f;
#pragma unroll 4
      for (int ii = 0; ii < 64; ++ii) {
        int off = (ib + ii) * LDW + j;
        float e = __expf(b2f(sc[off]) - mg);
        sc[off] = f2b(e);
        sum += e;
      }
      red[half * 128 + j] = sum;
      __syncthreads();
    }
    // fold 1/colsum into vT rows: vhat[j][e] = v[j][e] / sum_j
    {
      int e = tid >> 3;
      int jb = (tid & 7) * 16;
#pragma unroll
      for (int jj = 0; jj < 16; ++jj) {
        int j = jb + jj;
        float inv = 1.f / (red[j] + red[128 + j]);
        int off = e * LDW + j;
        vT[off] = f2b(b2f(vT[off]) * inv);
      }
    }
    __syncthreads();

    // ---------------- prod = exp @ vhat ----------------
    f32x4 p[2][2];
#pragma unroll
    for (int i = 0; i < 2; ++i)
#pragma unroll
      for (int j = 0; j < 2; ++j) p[i][j] = fz;
#pragma unroll
    for (int mt = 0; mt < 2; ++mt) {
      int rr = r0 + mt * 16;
#pragma unroll
      for (int kc = 0; kc < 4; ++kc) {
        bf16x8 a = *(const bf16x8*)&sc[(rr + l15) * LDW + kc * 32 + lh * 8];
#pragma unroll
        for (int nt = 0; nt < 2; ++nt) {
          bf16x8 bv8 = *(const bf16x8*)&vT[(nt * 16 + l15) * LDW + kc * 32 + lh * 8];
          p[mt][nt] = __builtin_amdgcn_mfma_f32_16x16x32_bf16(a, bv8, p[mt][nt], 0, 0, 0);
        }
      }
    }
    // stash prod (bf16) in qh for the out-proj A-operand
#pragma unroll
    for (int mt = 0; mt < 2; ++mt)
#pragma unroll
      for (int nt = 0; nt < 2; ++nt)
#pragma unroll
        for (int r = 0; r < 4; ++r)
          qh[(r0 + mt * 16 + lh * 4 + r) * LDT + nt * 16 + l15] = f2b(p[mt][nt][r]);
    __syncthreads();

    // ---------------- out += prod @ wo_h^T ----------------
#pragma unroll
    for (int mt = 0; mt < 2; ++mt) {
      bf16x8 a = *(const bf16x8*)&qh[(r0 + mt * 16 + l15) * LDT + lh * 8];
#pragma unroll
      for (int nt = 0; nt < 2; ++nt) {
        bf16x8 bw = *(const bf16x8*)&wob[(nt * 16 + l15) * 256 + h * 32 + lh * 8];
        oacc[mt][nt] = __builtin_amdgcn_mfma_f32_16x16x32_bf16(a, bw, oacc[mt][nt], 0, 0, 0);
      }
    }
    __syncthreads();  // qh/kh/vT/sc reused next head
  }

  // ---------------- epilogue: + bo + x ----------------
#pragma unroll
  for (int mt = 0; mt < 2; ++mt)
#pragma unroll
    for (int nt = 0; nt < 2; ++nt)
#pragma unroll
      for (int r = 0; r < 4; ++r) {
        int s_ = wid * 32 + mt * 16 + lh * 4 + r;
        int e_ = nt * 16 + l15;
        int idx = s_ * 32 + e_;
        out[b * INSZ + idx] = oacc[mt][nt][r] + bo[e_] + xb[idx];
      }
}

extern "C" void kernel_launch(void* const* d_in, const int* in_sizes, int n_in,
                              void* d_out, int out_size, void* d_ws, size_t ws_size,
                              hipStream_t stream) {
  const float* x = (const float*)d_in[0];
  const float* gamma = (const float*)d_in[1];
  const float* beta = (const float*)d_in[2];
  const float* wq = (const float*)d_in[3];
  const float* bq = (const float*)d_in[4];
  const float* wk = (const float*)d_in[5];
  const float* bk = (const float*)d_in[6];
  const float* wv = (const float*)d_in[7];
  const float* bv = (const float*)d_in[8];
  const float* wo = (const float*)d_in[9];
  const float* bo = (const float*)d_in[10];
  float* out = (float*)d_out;
  unsigned short* wsb = (unsigned short*)d_ws;

  cvt_w<<<128, 256, 0, stream>>>(wq, wk, wv, wo, wsb);
  mha_fused<<<BATCH, TPB, 0, stream>>>(x, gamma, beta, bq, bk, bv, bo, wsb, out);
}

// Round 2
// 97.390 us; speedup vs baseline: 1.5095x; 1.5095x over previous
//
#include <hip/hip_runtime.h>

#define BATCH 1024
#define INSZ 4096
#define SQ 128
#define EM 32
#define NH 8
#define TPB 256

typedef __attribute__((ext_vector_type(8))) __bf16 bf16x8;
typedef __attribute__((ext_vector_type(4))) __bf16 bf16x4;
typedef __attribute__((ext_vector_type(4))) float f32x4;

// Padded leading dims (bf16 elems)
#define LDT 40    // [128][32] tiles (xn, q, k/prod)
#define LDW 136   // [x][128] tiles (P, vT)

__global__ void cvt_w(const float* __restrict__ wq, const float* __restrict__ wk,
                      const float* __restrict__ wv, const float* __restrict__ wo,
                      __bf16* __restrict__ ws) {
  int i = blockIdx.x * blockDim.x + threadIdx.x;  // 0..32767
  const float* src = (i < 8192) ? wq : (i < 16384) ? wk : (i < 24576) ? wv : wo;
  ws[i] = (__bf16)src[i & 8191];
}

__global__ __launch_bounds__(TPB, 2) void mha_fused(
    const float* __restrict__ x, const float* __restrict__ gamma,
    const float* __restrict__ beta, const float* __restrict__ bq,
    const float* __restrict__ bk, const float* __restrict__ bv,
    const float* __restrict__ bo, const __bf16* __restrict__ wbf,
    float* __restrict__ out) {
  __shared__ __align__(16) __bf16 t_lds[SQ * LDT];  // xn  [128][32]
  __shared__ __align__(16) __bf16 qh[SQ * LDT];     // q (scaled) [s][f]
  __shared__ __align__(16) __bf16 kh[SQ * LDT];     // k [s][f]; later prod [s][e]
  __shared__ __align__(16) __bf16 vT[EM * LDW];     // v^T [32 f][128 s]
  __shared__ __align__(16) __bf16 sc[SQ * LDW];     // P [query][key], normalized
  __shared__ float red2[8];

  const int b = blockIdx.x;
  const int tid = threadIdx.x;
  const int lane = tid & 63;
  const int wid = tid >> 6;   // 4 waves; wave w owns rows [32w, 32w+32)
  const int l15 = lane & 15;
  const int lh = lane >> 4;   // 0..3

  const __bf16* wqb = wbf;
  const __bf16* wkb = wbf + 8192;
  const __bf16* wvb = wbf + 16384;
  const __bf16* wob = wbf + 24576;  // [32][256] row-major

  const float* xb = x + b * INSZ;
  const f32x4 fz = {0.f, 0.f, 0.f, 0.f};
  const float SCL = 0.17677669529663687f;  // 1/sqrt(32)

  // ---------------- LayerNorm ----------------
  float xv[16];
  float s = 0.f, sq = 0.f;
#pragma unroll
  for (int i = 0; i < 4; ++i) {
    float4 a = ((const float4*)(xb + tid * 16))[i];
    xv[4 * i] = a.x; xv[4 * i + 1] = a.y; xv[4 * i + 2] = a.z; xv[4 * i + 3] = a.w;
  }
#pragma unroll
  for (int i = 0; i < 16; ++i) { s += xv[i]; sq += xv[i] * xv[i]; }
#pragma unroll
  for (int o = 32; o > 0; o >>= 1) { s += __shfl_down(s, o); sq += __shfl_down(sq, o); }
  if (lane == 0) { red2[wid] = s; red2[4 + wid] = sq; }
  __syncthreads();
  s = red2[0] + red2[1] + red2[2] + red2[3];
  sq = red2[4] + red2[5] + red2[6] + red2[7];
  const float mu = s * (1.f / INSZ);
  const float var = fmaxf(sq * (1.f / INSZ) - mu * mu, 0.f);
  const float rs = rsqrtf(var + 1e-5f);
  {
    int base = tid * 16;
#pragma unroll
    for (int i = 0; i < 4; ++i) {
      float4 g4 = ((const float4*)(gamma + base))[i];
      float4 b4 = ((const float4*)(beta + base))[i];
      float gg[4] = {g4.x, g4.y, g4.z, g4.w};
      float bb[4] = {b4.x, b4.y, b4.z, b4.w};
#pragma unroll
      for (int k = 0; k < 4; ++k) {
        int idx = base + 4 * i + k;
        float xn = (xv[4 * i + k] - mu) * rs * gg[k] + bb[k];
        t_lds[(idx >> 5) * LDT + (idx & 31)] = (__bf16)xn;
      }
    }
  }
  __syncthreads();

  f32x4 oacc[2][2];
#pragma unroll
  for (int i = 0; i < 2; ++i)
#pragma unroll
    for (int j = 0; j < 2; ++j) oacc[i][j] = fz;

  const int r0 = wid * 32;

  for (int h = 0; h < NH; ++h) {
    // ---------- Q,K projections, transposed MFMA: D[f][s] = W·xn^T ----------
    // lane reg r: f = ft*16 + lh*4 + r (consecutive), s = r0 + st*16 + l15
    bf16x8 tA0 = *(const bf16x8*)&t_lds[(r0 + l15) * LDT + lh * 8];
    bf16x8 tA1 = *(const bf16x8*)&t_lds[(r0 + 16 + l15) * LDT + lh * 8];
#pragma unroll
    for (int ft = 0; ft < 2; ++ft) {
      int f0 = h * 32 + ft * 16;
      bf16x8 wqf = *(const bf16x8*)&wqb[(f0 + l15) * 32 + lh * 8];
      bf16x8 wkf = *(const bf16x8*)&wkb[(f0 + l15) * 32 + lh * 8];
      f32x4 bq4 = *(const f32x4*)&bq[f0 + lh * 4];
      f32x4 bk4 = *(const f32x4*)&bk[f0 + lh * 4];
#pragma unroll
      for (int st = 0; st < 2; ++st) {
        bf16x8 tB = (st == 0) ? tA0 : tA1;
        f32x4 dq = __builtin_amdgcn_mfma_f32_16x16x32_bf16(wqf, tB, fz, 0, 0, 0);
        f32x4 dk = __builtin_amdgcn_mfma_f32_16x16x32_bf16(wkf, tB, fz, 0, 0, 0);
        bf16x4 pq, pk;
#pragma unroll
        for (int r = 0; r < 4; ++r) {
          pq[r] = (__bf16)((dq[r] + bq4[r]) * SCL);
          pk[r] = (__bf16)(dk[r] + bk4[r]);
        }
        *(bf16x4*)&qh[(r0 + st * 16 + l15) * LDT + ft * 16 + lh * 4] = pq;
        *(bf16x4*)&kh[(r0 + st * 16 + l15) * LDT + ft * 16 + lh * 4] = pk;
      }
    }
    // ---------- V projection, standard: D[s][f], packed store into vT[f][s] ----------
#pragma unroll
    for (int nt = 0; nt < 2; ++nt) {
      int f0 = h * 32 + nt * 16;
      bf16x8 wvf = *(const bf16x8*)&wvb[(f0 + l15) * 32 + lh * 8];
      float bvs = bv[f0 + l15];
#pragma unroll
      for (int mt = 0; mt < 2; ++mt) {
        bf16x8 tA = (mt == 0) ? tA0 : tA1;
        f32x4 dv = __builtin_amdgcn_mfma_f32_16x16x32_bf16(tA, wvf, fz, 0, 0, 0);
        bf16x4 pv;
#pragma unroll
        for (int r = 0; r < 4; ++r) pv[r] = (__bf16)(dv[r] + bvs);
        *(bf16x4*)&vT[(nt * 16 + l15) * LDW + r0 + mt * 16 + lh * 4] = pv;
      }
    }
    __syncthreads();  // S1: qh, kh, vT ready

    // ---------- scoresT = K·q^T : D[j][i], wave-local over all queries ----------
    // lane reg r: j = r0 + mt*16 + lh*4 + r, i = it*16 + l15
    f32x4 st_[2][8];
#pragma unroll
    for (int it = 0; it < 8; ++it) {
      bf16x8 qb = *(const bf16x8*)&qh[(it * 16 + l15) * LDT + lh * 8];
#pragma unroll
      for (int mt = 0; mt < 2; ++mt) {
        bf16x8 ka = *(const bf16x8*)&kh[(r0 + mt * 16 + l15) * LDT + lh * 8];
        st_[mt][it] = __builtin_amdgcn_mfma_f32_16x16x32_bf16(ka, qb, fz, 0, 0, 0);
      }
    }

    // ---------- softmax over query axis: per j, reduce over (it, l15) ----------
    float inv[2][4];
#pragma unroll
    for (int mt = 0; mt < 2; ++mt)
#pragma unroll
      for (int r = 0; r < 4; ++r) {
        float m = st_[mt][0][r];
#pragma unroll
        for (int it = 1; it < 8; ++it) m = fmaxf(m, st_[mt][it][r]);
#pragma unroll
        for (int o = 1; o < 16; o <<= 1) m = fmaxf(m, __shfl_xor(m, o, 64));
        float ssum = 0.f;
#pragma unroll
        for (int it = 0; it < 8; ++it) {
          float e = __expf(st_[mt][it][r] - m);
          st_[mt][it][r] = e;
          ssum += e;
        }
#pragma unroll
        for (int o = 1; o < 16; o <<= 1) ssum += __shfl_xor(ssum, o, 64);
        inv[mt][r] = 1.f / ssum;
      }

    // ---------- P store: normalized, transposed back to [query][key], packed ----------
#pragma unroll
    for (int mt = 0; mt < 2; ++mt)
#pragma unroll
      for (int it = 0; it < 8; ++it) {
        bf16x4 pp;
#pragma unroll
        for (int r = 0; r < 4; ++r) pp[r] = (__bf16)(st_[mt][it][r] * inv[mt][r]);
        *(bf16x4*)&sc[(it * 16 + l15) * LDW + r0 + mt * 16 + lh * 4] = pp;
      }
    __syncthreads();  // S2: P ready

    // ---------- PV: D[e][q] = vT·P^T ; stash packed into kh[s][e] ----------
    f32x4 p2[2][2];
#pragma unroll
    for (int i = 0; i < 2; ++i)
#pragma unroll
      for (int j = 0; j < 2; ++j) p2[i][j] = fz;
#pragma unroll
    for (int kc = 0; kc < 4; ++kc) {
#pragma unroll
      for (int et = 0; et < 2; ++et) {
        bf16x8 va = *(const bf16x8*)&vT[(et * 16 + l15) * LDW + kc * 32 + lh * 8];
#pragma unroll
        for (int qt = 0; qt < 2; ++qt) {
          bf16x8 pb = *(const bf16x8*)&sc[(r0 + qt * 16 + l15) * LDW + kc * 32 + lh * 8];
          p2[et][qt] = __builtin_amdgcn_mfma_f32_16x16x32_bf16(va, pb, p2[et][qt], 0, 0, 0);
        }
      }
    }
    // lane reg r: e = et*16 + lh*4 + r (consecutive), q = r0 + qt*16 + l15
#pragma unroll
    for (int et = 0; et < 2; ++et)
#pragma unroll
      for (int qt = 0; qt < 2; ++qt) {
        bf16x4 pp;
#pragma unroll
        for (int r = 0; r < 4; ++r) pp[r] = (__bf16)p2[et][qt][r];
        *(bf16x4*)&kh[(r0 + qt * 16 + l15) * LDT + et * 16 + lh * 4] = pp;
      }

    // ---------- out += prod @ wo_h^T (same-wave kh read, no barrier needed) ----------
#pragma unroll
    for (int mt = 0; mt < 2; ++mt) {
      bf16x8 aa = *(const bf16x8*)&kh[(r0 + mt * 16 + l15) * LDT + lh * 8];
#pragma unroll
      for (int nt = 0; nt < 2; ++nt) {
        bf16x8 bw = *(const bf16x8*)&wob[(nt * 16 + l15) * 256 + h * 32 + lh * 8];
        oacc[mt][nt] = __builtin_amdgcn_mfma_f32_16x16x32_bf16(aa, bw, oacc[mt][nt], 0, 0, 0);
      }
    }
    __syncthreads();  // S3: all cross-wave reads of qh/vT/sc done before next head
  }

  // ---------------- epilogue: + bo + x ----------------
#pragma unroll
  for (int mt = 0; mt < 2; ++mt)
#pragma unroll
    for (int nt = 0; nt < 2; ++nt)
#pragma unroll
      for (int r = 0; r < 4; ++r) {
        int s_ = r0 + mt * 16 + lh * 4 + r;
        int e_ = nt * 16 + l15;
        int idx = s_ * 32 + e_;
        out[b * INSZ + idx] = oacc[mt][nt][r] + bo[e_] + xb[idx];
      }
}

extern "C" void kernel_launch(void* const* d_in, const int* in_sizes, int n_in,
                              void* d_out, int out_size, void* d_ws, size_t ws_size,
                              hipStream_t stream) {
  const float* x = (const float*)d_in[0];
  const float* gamma = (const float*)d_in[1];
  const float* beta = (const float*)d_in[2];
  const float* wq = (const float*)d_in[3];
  const float* bq = (const float*)d_in[4];
  const float* wk = (const float*)d_in[5];
  const float* bk = (const float*)d_in[6];
  const float* wv = (const float*)d_in[7];
  const float* bv = (const float*)d_in[8];
  const float* wo = (const float*)d_in[9];
  const float* bo = (const float*)d_in[10];
  float* out = (float*)d_out;
  __bf16* wsb = (__bf16*)d_ws;

  cvt_w<<<128, 256, 0, stream>>>(wq, wk, wv, wo, wsb);
  mha_fused<<<BATCH, TPB, 0, stream>>>(x, gamma, beta, bq, bk, bv, bo, wsb, out);
}

// Round 3
// 77.964 us; speedup vs baseline: 1.8857x; 1.2492x over previous
//
#include <hip/hip_runtime.h>

#define BATCH 1024
#define INSZ 4096
#define SQ 128
#define EM 32
#define NH 8
#define TPB 256

typedef __attribute__((ext_vector_type(8))) __bf16 bf16x8;
typedef __attribute__((ext_vector_type(4))) __bf16 bf16x4;
typedef __attribute__((ext_vector_type(4))) float f32x4;

// Padded leading dims (bf16 elems)
#define LDT 40    // [128][32] tiles (xn, q, k/prod): 80B rows, slot stride 5 (gcd(5,8)=1)
#define LDW 136   // [x][128] tiles (P, vT): 272B rows, slot stride 17 (odd)

__global__ void cvt_w(const float* __restrict__ wq, const float* __restrict__ wk,
                      const float* __restrict__ wv, const float* __restrict__ wo,
                      __bf16* __restrict__ ws) {
  int i = blockIdx.x * blockDim.x + threadIdx.x;  // 0..32767
  const float* src = (i < 8192) ? wq : (i < 16384) ? wk : (i < 24576) ? wv : wo;
  ws[i] = (__bf16)src[i & 8191];
}

__global__ __launch_bounds__(TPB, 2) void mha_fused(
    const float* __restrict__ x, const float* __restrict__ gamma,
    const float* __restrict__ beta, const float* __restrict__ bq,
    const float* __restrict__ bk, const float* __restrict__ bv,
    const float* __restrict__ bo, const __bf16* __restrict__ wbf,
    float* __restrict__ out) {
  __shared__ __align__(16) __bf16 t_lds[SQ * LDT];  // xn  [128][32]
  __shared__ __align__(16) __bf16 qh[SQ * LDT];     // q (scaled) [s][f]
  __shared__ __align__(16) __bf16 kh[SQ * LDT];     // k [s][f]; later prod [s][e]
  __shared__ __align__(16) __bf16 vT[EM * LDW];     // v^T [32 f][128 s]
  __shared__ __align__(16) __bf16 sc[SQ * LDW];     // P [query][key], normalized
  __shared__ float red2[8];

  const int b = blockIdx.x;
  const int tid = threadIdx.x;
  const int lane = tid & 63;
  const int wid = tid >> 6;   // 4 waves; wave w owns rows [32w, 32w+32)
  const int l15 = lane & 15;
  const int lh = lane >> 4;   // 0..3

  const __bf16* wqb = wbf;
  const __bf16* wkb = wbf + 8192;
  const __bf16* wvb = wbf + 16384;
  const __bf16* wob = wbf + 24576;  // [32][256] row-major

  const float* xb = x + b * INSZ;
  const f32x4 fz = {0.f, 0.f, 0.f, 0.f};
  // 1/sqrt(32) * log2(e): scores come out pre-scaled for exp2; softmax uses m=0
  // (shift-invariant; |scores| is O(5) for this data, no overflow possible).
  const float CQ = 0.2550564403f;

  // ---------------- LayerNorm ----------------
  float xv[16];
  float s = 0.f, sq = 0.f;
#pragma unroll
  for (int i = 0; i < 4; ++i) {
    float4 a = ((const float4*)(xb + tid * 16))[i];
    xv[4 * i] = a.x; xv[4 * i + 1] = a.y; xv[4 * i + 2] = a.z; xv[4 * i + 3] = a.w;
  }
#pragma unroll
  for (int i = 0; i < 16; ++i) { s += xv[i]; sq += xv[i] * xv[i]; }
#pragma unroll
  for (int o = 32; o > 0; o >>= 1) { s += __shfl_down(s, o); sq += __shfl_down(sq, o); }
  if (lane == 0) { red2[wid] = s; red2[4 + wid] = sq; }
  __syncthreads();
  s = red2[0] + red2[1] + red2[2] + red2[3];
  sq = red2[4] + red2[5] + red2[6] + red2[7];
  const float mu = s * (1.f / INSZ);
  const float var = fmaxf(sq * (1.f / INSZ) - mu * mu, 0.f);
  const float rs = rsqrtf(var + 1e-5f);
  {
    int base = tid * 16;
#pragma unroll
    for (int i = 0; i < 4; ++i) {
      float4 g4 = ((const float4*)(gamma + base))[i];
      float4 b4 = ((const float4*)(beta + base))[i];
      float gg[4] = {g4.x, g4.y, g4.z, g4.w};
      float bb[4] = {b4.x, b4.y, b4.z, b4.w};
#pragma unroll
      for (int k = 0; k < 4; ++k) {
        int idx = base + 4 * i + k;
        float xn = (xv[4 * i + k] - mu) * rs * gg[k] + bb[k];
        t_lds[(idx >> 5) * LDT + (idx & 31)] = (__bf16)xn;
      }
    }
  }
  // NOTE: no barrier here — each wave reads only its own 32 rows of t_lds,
  // which were written by the same wave (row = tid/2).

  f32x4 oacc[2][2];
#pragma unroll
  for (int i = 0; i < 2; ++i)
#pragma unroll
    for (int j = 0; j < 2; ++j) oacc[i][j] = fz;

  const int r0 = wid * 32;

  // xn fragments are head-invariant: hoist out of the head loop.
  bf16x8 tA0 = *(const bf16x8*)&t_lds[(r0 + l15) * LDT + lh * 8];
  bf16x8 tA1 = *(const bf16x8*)&t_lds[(r0 + 16 + l15) * LDT + lh * 8];

  for (int h = 0; h < NH; ++h) {
    // ---------- Q,K projections, transposed MFMA: D[f][s] = W·xn^T ----------
#pragma unroll
    for (int ft = 0; ft < 2; ++ft) {
      int f0 = h * 32 + ft * 16;
      bf16x8 wqf = *(const bf16x8*)&wqb[(f0 + l15) * 32 + lh * 8];
      bf16x8 wkf = *(const bf16x8*)&wkb[(f0 + l15) * 32 + lh * 8];
      f32x4 bq4 = *(const f32x4*)&bq[f0 + lh * 4];
      f32x4 bk4 = *(const f32x4*)&bk[f0 + lh * 4];
#pragma unroll
      for (int st = 0; st < 2; ++st) {
        bf16x8 tB = (st == 0) ? tA0 : tA1;
        f32x4 dq = __builtin_amdgcn_mfma_f32_16x16x32_bf16(wqf, tB, fz, 0, 0, 0);
        f32x4 dk = __builtin_amdgcn_mfma_f32_16x16x32_bf16(wkf, tB, fz, 0, 0, 0);
        bf16x4 pq, pk;
#pragma unroll
        for (int r = 0; r < 4; ++r) {
          pq[r] = (__bf16)((dq[r] + bq4[r]) * CQ);
          pk[r] = (__bf16)(dk[r] + bk4[r]);
        }
        *(bf16x4*)&qh[(r0 + st * 16 + l15) * LDT + ft * 16 + lh * 4] = pq;
        *(bf16x4*)&kh[(r0 + st * 16 + l15) * LDT + ft * 16 + lh * 4] = pk;
      }
    }
    // ---------- V projection, standard: D[s][f], packed store into vT[f][s] ----------
#pragma unroll
    for (int nt = 0; nt < 2; ++nt) {
      int f0 = h * 32 + nt * 16;
      bf16x8 wvf = *(const bf16x8*)&wvb[(f0 + l15) * 32 + lh * 8];
      float bvs = bv[f0 + l15];
#pragma unroll
      for (int mt = 0; mt < 2; ++mt) {
        bf16x8 tA = (mt == 0) ? tA0 : tA1;
        f32x4 dv = __builtin_amdgcn_mfma_f32_16x16x32_bf16(tA, wvf, fz, 0, 0, 0);
        bf16x4 pv;
#pragma unroll
        for (int r = 0; r < 4; ++r) pv[r] = (__bf16)(dv[r] + bvs);
        *(bf16x4*)&vT[(nt * 16 + l15) * LDW + r0 + mt * 16 + lh * 4] = pv;
      }
    }
    __syncthreads();  // S1: qh, kh, vT ready

    // ---------- scoresT = K·q^T : D[j][i], wave-local over all queries ----------
    // lane reg r: j = r0 + mt*16 + lh*4 + r, i = it*16 + l15
    bf16x8 ka0 = *(const bf16x8*)&kh[(r0 + l15) * LDT + lh * 8];
    bf16x8 ka1 = *(const bf16x8*)&kh[(r0 + 16 + l15) * LDT + lh * 8];
    f32x4 st_[2][8];
    __builtin_amdgcn_s_setprio(1);
#pragma unroll
    for (int it = 0; it < 8; ++it) {
      bf16x8 qb = *(const bf16x8*)&qh[(it * 16 + l15) * LDT + lh * 8];
      st_[0][it] = __builtin_amdgcn_mfma_f32_16x16x32_bf16(ka0, qb, fz, 0, 0, 0);
      st_[1][it] = __builtin_amdgcn_mfma_f32_16x16x32_bf16(ka1, qb, fz, 0, 0, 0);
    }
    __builtin_amdgcn_s_setprio(0);

    // ---------- softmax over query axis (m=0): P = exp2(s'), col sums ----------
    float inv[2][4];
#pragma unroll
    for (int mt = 0; mt < 2; ++mt)
#pragma unroll
      for (int r = 0; r < 4; ++r) {
        float ssum = 0.f;
#pragma unroll
        for (int it = 0; it < 8; ++it) {
          float e = __builtin_amdgcn_exp2f(st_[mt][it][r]);
          st_[mt][it][r] = e;
          ssum += e;
        }
#pragma unroll
        for (int o = 1; o < 16; o <<= 1) ssum += __shfl_xor(ssum, o, 64);
        inv[mt][r] = __builtin_amdgcn_rcpf(ssum);
      }

    // ---------- P store: normalized, transposed back to [query][key], packed ----------
#pragma unroll
    for (int mt = 0; mt < 2; ++mt)
#pragma unroll
      for (int it = 0; it < 8; ++it) {
        bf16x4 pp;
#pragma unroll
        for (int r = 0; r < 4; ++r) pp[r] = (__bf16)(st_[mt][it][r] * inv[mt][r]);
        *(bf16x4*)&sc[(it * 16 + l15) * LDW + r0 + mt * 16 + lh * 4] = pp;
      }
    __syncthreads();  // S2: P ready

    // ---------- PV: D[e][q] = vT·P^T ; stash packed into kh[s][e] ----------
    f32x4 p2[2][2];
#pragma unroll
    for (int i = 0; i < 2; ++i)
#pragma unroll
      for (int j = 0; j < 2; ++j) p2[i][j] = fz;
    __builtin_amdgcn_s_setprio(1);
#pragma unroll
    for (int kc = 0; kc < 4; ++kc) {
      bf16x8 pb0 = *(const bf16x8*)&sc[(r0 + l15) * LDW + kc * 32 + lh * 8];
      bf16x8 pb1 = *(const bf16x8*)&sc[(r0 + 16 + l15) * LDW + kc * 32 + lh * 8];
      bf16x8 va0 = *(const bf16x8*)&vT[(l15) * LDW + kc * 32 + lh * 8];
      bf16x8 va1 = *(const bf16x8*)&vT[(16 + l15) * LDW + kc * 32 + lh * 8];
      p2[0][0] = __builtin_amdgcn_mfma_f32_16x16x32_bf16(va0, pb0, p2[0][0], 0, 0, 0);
      p2[0][1] = __builtin_amdgcn_mfma_f32_16x16x32_bf16(va0, pb1, p2[0][1], 0, 0, 0);
      p2[1][0] = __builtin_amdgcn_mfma_f32_16x16x32_bf16(va1, pb0, p2[1][0], 0, 0, 0);
      p2[1][1] = __builtin_amdgcn_mfma_f32_16x16x32_bf16(va1, pb1, p2[1][1], 0, 0, 0);
    }
    __builtin_amdgcn_s_setprio(0);
    // lane reg r: e = et*16 + lh*4 + r (consecutive), q = r0 + qt*16 + l15
#pragma unroll
    for (int et = 0; et < 2; ++et)
#pragma unroll
      for (int qt = 0; qt < 2; ++qt) {
        bf16x4 pp;
#pragma unroll
        for (int r = 0; r < 4; ++r) pp[r] = (__bf16)p2[et][qt][r];
        *(bf16x4*)&kh[(r0 + qt * 16 + l15) * LDT + et * 16 + lh * 4] = pp;
      }

    // ---------- out += prod @ wo_h^T (same-wave kh read, no barrier needed) ----------
    {
      bf16x8 wo0 = *(const bf16x8*)&wob[(l15) * 256 + h * 32 + lh * 8];
      bf16x8 wo1 = *(const bf16x8*)&wob[(16 + l15) * 256 + h * 32 + lh * 8];
#pragma unroll
      for (int mt = 0; mt < 2; ++mt) {
        bf16x8 aa = *(const bf16x8*)&kh[(r0 + mt * 16 + l15) * LDT + lh * 8];
        oacc[mt][0] = __builtin_amdgcn_mfma_f32_16x16x32_bf16(aa, wo0, oacc[mt][0], 0, 0, 0);
        oacc[mt][1] = __builtin_amdgcn_mfma_f32_16x16x32_bf16(aa, wo1, oacc[mt][1], 0, 0, 0);
      }
    }
    if (h < NH - 1) __syncthreads();  // S3: cross-wave reads done before next proj writes
  }

  // ---------------- epilogue: + bo + x ----------------
#pragma unroll
  for (int mt = 0; mt < 2; ++mt)
#pragma unroll
    for (int nt = 0; nt < 2; ++nt)
#pragma unroll
      for (int r = 0; r < 4; ++r) {
        int s_ = r0 + mt * 16 + lh * 4 + r;
        int e_ = nt * 16 + l15;
        int idx = s_ * 32 + e_;
        out[b * INSZ + idx] = oacc[mt][nt][r] + bo[e_] + xb[idx];
      }
}

extern "C" void kernel_launch(void* const* d_in, const int* in_sizes, int n_in,
                              void* d_out, int out_size, void* d_ws, size_t ws_size,
                              hipStream_t stream) {
  const float* x = (const float*)d_in[0];
  const float* gamma = (const float*)d_in[1];
  const float* beta = (const float*)d_in[2];
  const float* wq = (const float*)d_in[3];
  const float* bq = (const float*)d_in[4];
  const float* wk = (const float*)d_in[5];
  const float* bk = (const float*)d_in[6];
  const float* wv = (const float*)d_in[7];
  const float* bv = (const float*)d_in[8];
  const float* wo = (const float*)d_in[9];
  const float* bo = (const float*)d_in[10];
  float* out = (float*)d_out;
  __bf16* wsb = (__bf16*)d_ws;

  cvt_w<<<128, 256, 0, stream>>>(wq, wk, wv, wo, wsb);
  mha_fused<<<BATCH, TPB, 0, stream>>>(x, gamma, beta, bq, bk, bv, bo, wsb, out);
}

// Round 4
// 77.892 us; speedup vs baseline: 1.8874x; 1.0009x over previous
//
#include <hip/hip_runtime.h>

#define BATCH 1024
#define INSZ 4096
#define SQ 128
#define EM 32
#define NH 8
#define TPB 256

typedef __attribute__((ext_vector_type(8))) __bf16 bf16x8;
typedef __attribute__((ext_vector_type(4))) __bf16 bf16x4;
typedef __attribute__((ext_vector_type(4))) float f32x4;

// Padded leading dims (bf16 elems)
#define LDT 40    // [128][32] tiles (xn/q/k/prod): 80B rows; balanced banks for b64/b128
#define LDW 136   // [x][128] tiles (P, vT): 272B rows; balanced banks for b64/b128

__global__ void cvt_w(const float* __restrict__ wq, const float* __restrict__ wk,
                      const float* __restrict__ wv, const float* __restrict__ wo,
                      __bf16* __restrict__ ws) {
  int i = blockIdx.x * blockDim.x + threadIdx.x;  // 0..32767
  const float* src = (i < 8192) ? wq : (i < 16384) ? wk : (i < 24576) ? wv : wo;
  ws[i] = (__bf16)src[i & 8191];
}

// LDS budget: R(34816) + kh(10240) + vT(8704) + red2(32) = 53792 B  ->  3 blocks/CU.
// R holds, with disjoint lifetimes: xn (LDT stride, pre-loop) / q staging (LDT
// stride, until scores) / P matrix (LDW stride, P-store..PV). One extra barrier
// per head (S2a) enforces the qh->sc transition.
__global__ __launch_bounds__(TPB, 3) void mha_fused(
    const float* __restrict__ x, const float* __restrict__ gamma,
    const float* __restrict__ beta, const float* __restrict__ bq,
    const float* __restrict__ bk, const float* __restrict__ bv,
    const float* __restrict__ bo, const __bf16* __restrict__ wbf,
    float* __restrict__ out) {
  __shared__ __align__(16) __bf16 R[SQ * LDW];    // xn/q (LDT) | P (LDW)
  __shared__ __align__(16) __bf16 kh[SQ * LDT];   // k [s][f]; later prod [s][e] (wave-local)
  __shared__ __align__(16) __bf16 vT[EM * LDW];   // v^T [32 f][128 s]
  __shared__ float red2[8];

  const int b = blockIdx.x;
  const int tid = threadIdx.x;
  const int lane = tid & 63;
  const int wid = tid >> 6;   // 4 waves; wave w owns rows [32w, 32w+32)
  const int l15 = lane & 15;
  const int lh = lane >> 4;   // 0..3

  const __bf16* wqb = wbf;
  const __bf16* wkb = wbf + 8192;
  const __bf16* wvb = wbf + 16384;
  const __bf16* wob = wbf + 24576;  // [32][256] row-major

  const float* xb = x + b * INSZ;
  const f32x4 fz = {0.f, 0.f, 0.f, 0.f};
  // 1/sqrt(32) * log2(e): scores pre-scaled for exp2; softmax uses m=0
  // (shift-invariant; |scores| O(5) for LN'd data, no overflow risk).
  const float CQ = 0.2550564403f;

  // ---------------- LayerNorm ----------------
  float xv[16];
  float s = 0.f, sq = 0.f;
#pragma unroll
  for (int i = 0; i < 4; ++i) {
    float4 a = ((const float4*)(xb + tid * 16))[i];
    xv[4 * i] = a.x; xv[4 * i + 1] = a.y; xv[4 * i + 2] = a.z; xv[4 * i + 3] = a.w;
  }
#pragma unroll
  for (int i = 0; i < 16; ++i) { s += xv[i]; sq += xv[i] * xv[i]; }
#pragma unroll
  for (int o = 32; o > 0; o >>= 1) { s += __shfl_down(s, o); sq += __shfl_down(sq, o); }
  if (lane == 0) { red2[wid] = s; red2[4 + wid] = sq; }
  __syncthreads();
  s = red2[0] + red2[1] + red2[2] + red2[3];
  sq = red2[4] + red2[5] + red2[6] + red2[7];
  const float mu = s * (1.f / INSZ);
  const float var = fmaxf(sq * (1.f / INSZ) - mu * mu, 0.f);
  const float rs = rsqrtf(var + 1e-5f);
  {
    int base = tid * 16;
#pragma unroll
    for (int i = 0; i < 4; ++i) {
      float4 g4 = ((const float4*)(gamma + base))[i];
      float4 b4 = ((const float4*)(beta + base))[i];
      float gg[4] = {g4.x, g4.y, g4.z, g4.w};
      float bb[4] = {b4.x, b4.y, b4.z, b4.w};
#pragma unroll
      for (int k = 0; k < 4; ++k) {
        int idx = base + 4 * i + k;
        float xn = (xv[4 * i + k] - mu) * rs * gg[k] + bb[k];
        R[(idx >> 5) * LDT + (idx & 31)] = (__bf16)xn;  // wave-local rows
      }
    }
  }
  // No barrier: each wave reads back only its own 32 rows (written by itself).

  f32x4 oacc[2][2];
#pragma unroll
  for (int i = 0; i < 2; ++i)
#pragma unroll
    for (int j = 0; j < 2; ++j) oacc[i][j] = fz;

  const int r0 = wid * 32;

  // xn fragments are head-invariant: hoist to registers; R's xn role ends here.
  bf16x8 tA0 = *(const bf16x8*)&R[(r0 + l15) * LDT + lh * 8];
  bf16x8 tA1 = *(const bf16x8*)&R[(r0 + 16 + l15) * LDT + lh * 8];

  for (int h = 0; h < NH; ++h) {
    // ---------- Q,K projections, transposed MFMA: D[f][s] = W·xn^T ----------
#pragma unroll
    for (int ft = 0; ft < 2; ++ft) {
      int f0 = h * 32 + ft * 16;
      bf16x8 wqf = *(const bf16x8*)&wqb[(f0 + l15) * 32 + lh * 8];
      bf16x8 wkf = *(const bf16x8*)&wkb[(f0 + l15) * 32 + lh * 8];
      f32x4 bq4 = *(const f32x4*)&bq[f0 + lh * 4];
      f32x4 bk4 = *(const f32x4*)&bk[f0 + lh * 4];
#pragma unroll
      for (int st = 0; st < 2; ++st) {
        bf16x8 tB = (st == 0) ? tA0 : tA1;
        f32x4 dq = __builtin_amdgcn_mfma_f32_16x16x32_bf16(wqf, tB, fz, 0, 0, 0);
        f32x4 dk = __builtin_amdgcn_mfma_f32_16x16x32_bf16(wkf, tB, fz, 0, 0, 0);
        bf16x4 pq, pk;
#pragma unroll
        for (int r = 0; r < 4; ++r) {
          pq[r] = (__bf16)((dq[r] + bq4[r]) * CQ);
          pk[r] = (__bf16)(dk[r] + bk4[r]);
        }
        *(bf16x4*)&R[(r0 + st * 16 + l15) * LDT + ft * 16 + lh * 4] = pq;   // q staging
        *(bf16x4*)&kh[(r0 + st * 16 + l15) * LDT + ft * 16 + lh * 4] = pk;  // wave-local
      }
    }
    // ---------- V projection, standard: D[s][f], packed store into vT[f][s] ----------
#pragma unroll
    for (int nt = 0; nt < 2; ++nt) {
      int f0 = h * 32 + nt * 16;
      bf16x8 wvf = *(const bf16x8*)&wvb[(f0 + l15) * 32 + lh * 8];
      float bvs = bv[f0 + l15];
#pragma unroll
      for (int mt = 0; mt < 2; ++mt) {
        bf16x8 tA = (mt == 0) ? tA0 : tA1;
        f32x4 dv = __builtin_amdgcn_mfma_f32_16x16x32_bf16(tA, wvf, fz, 0, 0, 0);
        bf16x4 pv;
#pragma unroll
        for (int r = 0; r < 4; ++r) pv[r] = (__bf16)(dv[r] + bvs);
        *(bf16x4*)&vT[(nt * 16 + l15) * LDW + r0 + mt * 16 + lh * 4] = pv;
      }
    }
    // K fragments are wave-local (rows r0..r0+32 written by this wave): load
    // before the barrier to shorten the post-barrier critical path.
    bf16x8 ka0 = *(const bf16x8*)&kh[(r0 + l15) * LDT + lh * 8];
    bf16x8 ka1 = *(const bf16x8*)&kh[(r0 + 16 + l15) * LDT + lh * 8];
    __syncthreads();  // S1: q staging (R) + vT ready

    // ---------- scoresT = K·q^T : D[j][i], wave-local over all queries ----------
    // lane reg r: j = r0 + mt*16 + lh*4 + r, i = it*16 + l15
    f32x4 st_[2][8];
    __builtin_amdgcn_s_setprio(1);
#pragma unroll
    for (int it = 0; it < 8; ++it) {
      bf16x8 qb = *(const bf16x8*)&R[(it * 16 + l15) * LDT + lh * 8];
      st_[0][it] = __builtin_amdgcn_mfma_f32_16x16x32_bf16(ka0, qb, fz, 0, 0, 0);
      st_[1][it] = __builtin_amdgcn_mfma_f32_16x16x32_bf16(ka1, qb, fz, 0, 0, 0);
    }
    __builtin_amdgcn_s_setprio(0);

    // ---------- softmax over query axis (m=0): P = exp2(s'), col sums ----------
    float inv[2][4];
#pragma unroll
    for (int mt = 0; mt < 2; ++mt)
#pragma unroll
      for (int r = 0; r < 4; ++r) {
        float ssum = 0.f;
#pragma unroll
        for (int it = 0; it < 8; ++it) {
          float e = __builtin_amdgcn_exp2f(st_[mt][it][r]);
          st_[mt][it][r] = e;
          ssum += e;
        }
#pragma unroll
        for (int o = 1; o < 16; o <<= 1) ssum += __shfl_xor(ssum, o, 64);
        inv[mt][r] = __builtin_amdgcn_rcpf(ssum);
      }
    __syncthreads();  // S2a: all q-staging reads of R done; safe to repurpose as P

    // ---------- P store: normalized, transposed back to [query][key], packed ----------
#pragma unroll
    for (int mt = 0; mt < 2; ++mt)
#pragma unroll
      for (int it = 0; it < 8; ++it) {
        bf16x4 pp;
#pragma unroll
        for (int r = 0; r < 4; ++r) pp[r] = (__bf16)(st_[mt][it][r] * inv[mt][r]);
        *(bf16x4*)&R[(it * 16 + l15) * LDW + r0 + mt * 16 + lh * 4] = pp;
      }
    __syncthreads();  // S2b: P ready

    // ---------- PV: D[e][q] = vT·P^T ; stash packed into kh[s][e] ----------
    f32x4 p2[2][2];
#pragma unroll
    for (int i = 0; i < 2; ++i)
#pragma unroll
      for (int j = 0; j < 2; ++j) p2[i][j] = fz;
    __builtin_amdgcn_s_setprio(1);
#pragma unroll
    for (int kc = 0; kc < 4; ++kc) {
      bf16x8 pb0 = *(const bf16x8*)&R[(r0 + l15) * LDW + kc * 32 + lh * 8];
      bf16x8 pb1 = *(const bf16x8*)&R[(r0 + 16 + l15) * LDW + kc * 32 + lh * 8];
      bf16x8 va0 = *(const bf16x8*)&vT[(l15) * LDW + kc * 32 + lh * 8];
      bf16x8 va1 = *(const bf16x8*)&vT[(16 + l15) * LDW + kc * 32 + lh * 8];
      p2[0][0] = __builtin_amdgcn_mfma_f32_16x16x32_bf16(va0, pb0, p2[0][0], 0, 0, 0);
      p2[0][1] = __builtin_amdgcn_mfma_f32_16x16x32_bf16(va0, pb1, p2[0][1], 0, 0, 0);
      p2[1][0] = __builtin_amdgcn_mfma_f32_16x16x32_bf16(va1, pb0, p2[1][0], 0, 0, 0);
      p2[1][1] = __builtin_amdgcn_mfma_f32_16x16x32_bf16(va1, pb1, p2[1][1], 0, 0, 0);
    }
    __builtin_amdgcn_s_setprio(0);
    // lane reg r: e = et*16 + lh*4 + r (consecutive), q = r0 + qt*16 + l15
#pragma unroll
    for (int et = 0; et < 2; ++et)
#pragma unroll
      for (int qt = 0; qt < 2; ++qt) {
        bf16x4 pp;
#pragma unroll
        for (int r = 0; r < 4; ++r) pp[r] = (__bf16)p2[et][qt][r];
        *(bf16x4*)&kh[(r0 + qt * 16 + l15) * LDT + et * 16 + lh * 4] = pp;
      }

    // ---------- out += prod @ wo_h^T (same-wave kh read, no barrier needed) ----------
    {
      bf16x8 wo0 = *(const bf16x8*)&wob[(l15) * 256 + h * 32 + lh * 8];
      bf16x8 wo1 = *(const bf16x8*)&wob[(16 + l15) * 256 + h * 32 + lh * 8];
#pragma unroll
      for (int mt = 0; mt < 2; ++mt) {
        bf16x8 aa = *(const bf16x8*)&kh[(r0 + mt * 16 + l15) * LDT + lh * 8];
        oacc[mt][0] = __builtin_amdgcn_mfma_f32_16x16x32_bf16(aa, wo0, oacc[mt][0], 0, 0, 0);
        oacc[mt][1] = __builtin_amdgcn_mfma_f32_16x16x32_bf16(aa, wo1, oacc[mt][1], 0, 0, 0);
      }
    }
    if (h < NH - 1) __syncthreads();  // S3: PV reads of R/vT done before next head writes
  }

  // ---------------- epilogue: + bo + x ----------------
#pragma unroll
  for (int mt = 0; mt < 2; ++mt)
#pragma unroll
    for (int nt = 0; nt < 2; ++nt)
#pragma unroll
      for (int r = 0; r < 4; ++r) {
        int s_ = r0 + mt * 16 + lh * 4 + r;
        int e_ = nt * 16 + l15;
        int idx = s_ * 32 + e_;
        out[b * INSZ + idx] = oacc[mt][nt][r] + bo[e_] + xb[idx];
      }
}

extern "C" void kernel_launch(void* const* d_in, const int* in_sizes, int n_in,
                              void* d_out, int out_size, void* d_ws, size_t ws_size,
                              hipStream_t stream) {
  const float* x = (const float*)d_in[0];
  const float* gamma = (const float*)d_in[1];
  const float* beta = (const float*)d_in[2];
  const float* wq = (const float*)d_in[3];
  const float* bq = (const float*)d_in[4];
  const float* wk = (const float*)d_in[5];
  const float* bk = (const float*)d_in[6];
  const float* wv = (const float*)d_in[7];
  const float* bv = (const float*)d_in[8];
  const float* wo = (const float*)d_in[9];
  const float* bo = (const float*)d_in[10];
  float* out = (float*)d_out;
  __bf16* wsb = (__bf16*)d_ws;

  cvt_w<<<128, 256, 0, stream>>>(wq, wk, wv, wo, wsb);
  mha_fused<<<BATCH, TPB, 0, stream>>>(x, gamma, beta, bq, bk, bv, bo, wsb, out);
}